// Round 9
// baseline (401.234 us; speedup 1.0000x reference)
//
#include <hip/hip_runtime.h>
#include <hip/hip_bf16.h>

// DCNv2 CrossNet on MI355X — fused 3-layer kernel, v12.
// One-axis change vs v11 (which tied v8 at ~228 us): prefetch LEAD TIME.
// Evidence: ~2.5k cyc per slice-interval vs ~300-500 achievable; ~170 MB
// weight HBM refetch => ~20% of ring loads miss L2; a distance-2 ring
// self-locks at interval ~ miss_latency/2. v12: slices 16KB->8KB (G1 =
// half-ks, G3 = quarter-ks), ring 3x16KB -> 6x8KB (same 48 KB), distance
// 2 -> 5 (steady lead = 5 intervals; prologue slices lead = whole gate
// phase). Staging: each of 16 waves stages 512 B/slice via exec-masked
// (lane<32) global_load_lds. Waves compute only on matching sub-slices
// (G1: h == wc>>2; G3: q == wc>>1) — same MFMA totals, half-size intervals.
// Soundness: in-order vmem retirement => "slice s resident" <=>
// vmcnt <= min(4, 31-s); slot (s+5)%6 == (s-1)%6 freed by interval-s
// barrier's lgkm drain. Also: x loads back to PLAIN (nt correlated with
// +60-76 MB on both traffic counters, v10b/v11 vs v8); bias load moved
// post-G3 (outside the pipeline's vmcnt window).
//
// Shapes: x[32768,512]; Vs[3,4,64,512]; Cs[3,4,64,64]; Us[3,4,512,64];
//         bias[3,512]; gate_w[512,4].

#define CROSS   3
#define ENUM    4
#define LR      64
#define ELD     256     // ENUM*LR
#define DIM     512
#define BATCH   32768
#define BT      64      // batch rows per block
#define NTHR    1024    // 16 waves

#define XL_W    520     // 512 + 8 pad (shorts)
#define Y_W     264     // 256 + 8 pad (shorts)

typedef __bf16 bf16x8 __attribute__((ext_vector_type(8)));
typedef float  f32x4  __attribute__((ext_vector_type(4)));
typedef unsigned short us;
typedef unsigned short us4 __attribute__((ext_vector_type(4)));

__device__ __forceinline__ us f2bf(float f) {
    return __builtin_bit_cast(us, (__bf16)f);
}
__device__ __forceinline__ float bf2f(us b) {
    unsigned int u = ((unsigned int)b) << 16;
    return __builtin_bit_cast(float, u);
}
// fast tanh: (e^2x - 1) / (e^2x + 1); inputs bounded by 0.05-scaled weights.
__device__ __forceinline__ float tanh_fast(float x) {
    float t = __expf(2.f * x);
    return (t - 1.f) * __builtin_amdgcn_rcpf(t + 1.f);
}

#define MFMA(a, b, c) __builtin_amdgcn_mfma_f32_16x16x32_bf16(a, b, c, 0, 0, 0)

// async global->LDS copy, 16 B per lane. LDS dest wave-uniform; HW writes
// lane l at dst + l*16. Global src is per-lane. Exec-masked lanes skip.
__device__ __forceinline__ void gload_lds16(const us* g, us* l) {
    __builtin_amdgcn_global_load_lds(
        (const __attribute__((address_space(1))) unsigned int*)g,
        (__attribute__((address_space(3))) unsigned int*)l, 16, 0, 0);
}

#define WAITN(n)  asm volatile("s_waitcnt vmcnt(" #n ")" ::: "memory")
#define SBAR0()   __builtin_amdgcn_sched_barrier(0)
// Barrier that does NOT drain vmcnt: ds-visibility (lgkmcnt) + s_barrier.
#define LBAR() do { SBAR0(); \
    asm volatile("s_waitcnt lgkmcnt(0)" ::: "memory"); \
    __builtin_amdgcn_s_barrier(); SBAR0(); } while (0)

// wait until own slice-s stage is resident: left = min(4, 31 - s) loads
// may remain outstanding. Constant-folds under full unroll.
__device__ __forceinline__ void wait_left(int left) {
    if (left >= 4)      WAITN(4);
    else if (left == 3) WAITN(3);
    else if (left == 2) WAITN(2);
    else if (left == 1) WAITN(1);
    else                WAITN(0);
}

// ---------------------------------------------------------------------------
// Swizzle prepass: fp32 weights -> bf16 MFMA-B fragment order, vectorized.
// frag[nt][ks][lane][8]: n = nt*16 + (lane&15), k = ks*32 + (lane>>4)*8 + j.
// ---------------------------------------------------------------------------
__global__ __launch_bounds__(64) void swz_all(
    const float* __restrict__ Vs, const float* __restrict__ Cs,
    const float* __restrict__ Us,
    us* __restrict__ Vf, us* __restrict__ Cf, us* __restrict__ Uf)
{
    int b = blockIdx.x;
    int lane = threadIdx.x;
    const float* src;
    us* dst;
    if (b < 768) {                       // V: [3][16 nt][16 ks]
        int i = b >> 8, t = b & 255;
        int nt = t >> 4, ks = t & 15;
        int n  = nt * 16 + (lane & 15);
        int k0 = ks * 32 + (lane >> 4) * 8;
        src = Vs + (size_t)i * ELD * DIM + (size_t)n * DIM + k0;
        dst = Vf + (size_t)i * ELD * DIM
            + ((size_t)(nt * 16 + ks) * 64 + lane) * 8;
    } else if (b < 1536) {               // U': [3][32 nt][8 ks], k = e*64+l
        int bb = b - 768;
        int i = bb >> 8, t = bb & 255;
        int nt = t >> 3, ks = t & 7;
        int n  = nt * 16 + (lane & 15);            // d
        int k0 = ks * 32 + (lane >> 4) * 8;        // e*64 + l
        int e = k0 >> 6, l0 = k0 & 63;
        src = Us + (size_t)i * ENUM * DIM * LR
            + (size_t)e * DIM * LR + (size_t)n * LR + l0;
        dst = Uf + (size_t)i * DIM * ELD
            + ((size_t)(nt * 8 + ks) * 64 + lane) * 8;
    } else {                             // C: [3][4 e][4 nt][2 ks]
        int bb = b - 1536;
        int i = bb >> 5, rest = bb & 31;
        int e = rest >> 3, t = rest & 7;
        int nt = t >> 1, ks = t & 1;
        int n  = nt * 16 + (lane & 15);
        int k0 = ks * 32 + (lane >> 4) * 8;
        src = Cs + (((size_t)(i * ENUM + e) * LR + n) * LR) + k0;
        dst = Cf + (size_t)i * ENUM * LR * LR
            + ((size_t)((e * 4 + nt) * 2 + ks) * 64 + lane) * 8;
    }
    f32x4 s0 = *reinterpret_cast<const f32x4*>(src);
    f32x4 s1 = *reinterpret_cast<const f32x4*>(src + 4);
    us4 p0, p1;
    p0[0] = f2bf(s0[0]); p0[1] = f2bf(s0[1]); p0[2] = f2bf(s0[2]); p0[3] = f2bf(s0[3]);
    p1[0] = f2bf(s1[0]); p1[1] = f2bf(s1[1]); p1[2] = f2bf(s1[2]); p1[3] = f2bf(s1[3]);
    *reinterpret_cast<us4*>(dst)     = p0;
    *reinterpret_cast<us4*>(dst + 4) = p1;
}

// ---------------------------------------------------------------------------
// Fused 3-layer kernel. Block: 64 rows, 1024 threads (16 waves), 1 block/CU.
// Wave split: rh = wave>>3 (row half), wc = wave&7 (col group).
// Thread ownership (16x16x32 D-layout, mt in 0..1):
//   row = rh*32 + mt*16 + quad*4 + r,  col(G3) = wc*64 + nt*16 + nl.
// G1 slices: s=(ks,h), 8 frags nt=8h..8h+7 (8 KB). Wave w stages 512 B:
//   frag 8h+(w>>1), byte-half (w&1), lanes<32. Wave (rh,wc) computes on
//   slices with h == wc>>2, reading local frags 2(wc&3)+{0,1}.
// G3 slices: s=(ks,q), 8 frags nt=8q..8q+7. Wave computes on q == wc>>1,
//   local frags 4(wc&1)+{0..3}.
// Ring: 6 x 8 KB slots, distance 5, one lgkm-barrier per slice, wait
//   vmcnt(min(4, 31-s)). All weight frags staged ONCE per block.
// ---------------------------------------------------------------------------
__global__ __launch_bounds__(NTHR, 4) void dcn_fused(
    const float* __restrict__ x,
    float* __restrict__ out,
    const us* __restrict__ Vf,
    const us* __restrict__ Cf,
    const us* __restrict__ Uf,
    const float* __restrict__ gw,
    const float* __restrict__ bias)
{
    __shared__ us xl_s[BT * XL_W];                   // 66560 B
    __shared__ __align__(16) us y_s[BT * Y_W];       // 33792 B (sc | Y | z)
    __shared__ us stg_s[6 * 4096];                   // 49152 B, 6 x 8KB slots
    __shared__ us gw_s[4 * 512];                     // 4096 B, gate_w [e][d]
    __shared__ __align__(16) float g_s[BT * ENUM];   // 1024 B
    // total 154624 B -> 1 block/CU, 16 waves (4/SIMD)
    float* sc = reinterpret_cast<float*>(y_s);       // gate partials alias

    const int tid  = threadIdx.x;
    const int wave = tid >> 6, lane = tid & 63;
    const int quad = lane >> 4, nl = lane & 15;
    const int rh = wave >> 3, wc = wave & 7;
    const int rh32 = rh * 32;
    const int row0 = blockIdx.x * BT;

    // staging roles (wave-uniform)
    const int sj = wave >> 1;            // frag-within-slice this wave stages
    const int sh = wave & 1;             // byte-half of that frag
    // consumption roles
    const int myh1 = wc >> 2, jb1 = (wc & 3) * 2;   // G1
    const int myq3 = wc >> 1, jb3 = (wc & 1) * 4;   // G3

#define ISSUE_V(s) do { if (lane < 32) gload_lds16( \
    Vl + ((size_t)(((((s) & 1) * 8 + sj) * 16 + ((s) >> 1)) * 64 \
                   + sh * 32 + lane) * 8), \
    stg_s + ((s) % 6) * 4096 + sj * 512 + sh * 256); } while (0)
#define ISSUE_U(s) do { if (lane < 32) gload_lds16( \
    Ul + ((size_t)(((((s) & 3) * 8 + sj) * 8 + ((s) >> 2)) * 64 \
                   + sh * 32 + lane) * 8), \
    stg_s + ((s) % 6) * 4096 + sj * 512 + sh * 256); } while (0)

    // ---- stage x -> xl_s (bf16): 64*128 = 8192 float4s, 8 per thread
    #pragma unroll
    for (int it = 0; it < 8; ++it) {
        int f4 = tid + it * NTHR;            // 0..8191
        int r = f4 >> 7, c4 = f4 & 127;
        f32x4 v = *reinterpret_cast<const f32x4*>(
            x + (size_t)(row0 + r) * DIM + c4 * 4);
        us4 p;
        p[0] = f2bf(v[0]); p[1] = f2bf(v[1]); p[2] = f2bf(v[2]); p[3] = f2bf(v[3]);
        *reinterpret_cast<us4*>(&xl_s[r * XL_W + c4 * 4]) = p;
    }
    // ---- stage gate_w -> gw_s[e][d] (bf16), 2 elems/thread
    #pragma unroll
    for (int j = 0; j < 2; ++j) {
        int idx = tid * 2 + j;               // 0..2047
        int e = idx >> 9, d = idx & 511;
        gw_s[idx] = f2bf(gw[(size_t)d * ENUM + e]);
    }
    LBAR();                                  // entry: xl_s + gw_s published

    // ---- x0 packed bf16 in regs (thread's ownership elements)
    unsigned int x0p[2][4][2];
    #pragma unroll
    for (int mt = 0; mt < 2; ++mt)
        #pragma unroll
        for (int nt = 0; nt < 4; ++nt) {
            int rb = rh32 + mt * 16 + quad * 4;
            int col = wc * 64 + nt * 16 + nl;
            unsigned int b0 = xl_s[(rb + 0) * XL_W + col];
            unsigned int b1 = xl_s[(rb + 1) * XL_W + col];
            unsigned int b2 = xl_s[(rb + 2) * XL_W + col];
            unsigned int b3 = xl_s[(rb + 3) * XL_W + col];
            x0p[mt][nt][0] = b0 | (b1 << 16);
            x0p[mt][nt][1] = b2 | (b3 << 16);
        }

    const int e = wc >> 1, h = wc & 1;       // GEMM2 roles

    #pragma unroll 1
    for (int layer = 0; layer < CROSS; ++layer) {
        const us* Vl = Vf + (size_t)layer * ELD * DIM;
        const us* Cl = Cf + (size_t)layer * ENUM * LR * LR;
        const us* Ul = Uf + (size_t)layer * DIM * ELD;
        const float* bl = bias + layer * DIM;

        // ---- C fragments (4 vmem loads; retired before V0 by in-order)
        bf16x8 creg[2][2];
        #pragma unroll
        for (int ks = 0; ks < 2; ++ks)
            #pragma unroll
            for (int nt = 0; nt < 2; ++nt)
                creg[ks][nt] = *reinterpret_cast<const bf16x8*>(
                    &Cl[((size_t)((e * 4 + h * 2 + nt) * 2 + ks) * 64 + lane) * 8]);

        // ---- V ring prologue: 5 slices in flight before the gate phase
        ISSUE_V(0); ISSUE_V(1); ISSUE_V(2); ISSUE_V(3); ISSUE_V(4);
        LBAR();                              // A: xl_s (prev epilogue) ready

        // ---- gate partials: thread (row, e, quarter) does 128 MACs
        {
            int grow = tid >> 4, ge = (tid >> 2) & 3, gq = tid & 3;
            float gp = 0.f;
            #pragma unroll
            for (int dd = 0; dd < 16; ++dd) {
                int d0 = gq * 128 + ((dd + gq * 4) & 15) * 8;
                bf16x8 xa = *reinterpret_cast<const bf16x8*>(
                    &xl_s[grow * XL_W + d0]);
                bf16x8 wa = *reinterpret_cast<const bf16x8*>(
                    &gw_s[ge * 512 + d0]);
                #pragma unroll
                for (int j = 0; j < 8; ++j)
                    gp += (float)xa[j] * (float)wa[j];
            }
            sc[tid] = gp;
        }
        LBAR();                              // B: partials published
        if (tid < 256)
            g_s[tid] = sc[tid * 4] + sc[tid * 4 + 1]
                     + sc[tid * 4 + 2] + sc[tid * 4 + 3];

        // ---- GEMM1: Y = tanh(xl @ V^T); 32 half-ks slices
        f32x4 acc1[2][2];
        acc1[0][0] = (f32x4)0.f; acc1[0][1] = (f32x4)0.f;
        acc1[1][0] = (f32x4)0.f; acc1[1][1] = (f32x4)0.f;
        #pragma unroll
        for (int s = 0; s < 32; ++s) {
            wait_left(31 - s);
            LBAR();                          // slice s ready; slot (s+5)%6 free
            if (s + 5 < 32) { ISSUE_V(s + 5); }
            if ((s & 1) == myh1) {
                const int ks = s >> 1;
                bf16x8 a0 = *reinterpret_cast<const bf16x8*>(
                    &xl_s[(rh32 + nl) * XL_W + ks * 32 + quad * 8]);
                bf16x8 a1 = *reinterpret_cast<const bf16x8*>(
                    &xl_s[(rh32 + 16 + nl) * XL_W + ks * 32 + quad * 8]);
                const us* sl = stg_s + (s % 6) * 4096;
                #pragma unroll
                for (int nt = 0; nt < 2; ++nt) {
                    bf16x8 b = *reinterpret_cast<const bf16x8*>(
                        &sl[(jb1 + nt) * 512 + lane * 8]);
                    acc1[0][nt] = MFMA(a0, b, acc1[0][nt]);
                    acc1[1][nt] = MFMA(a1, b, acc1[1][nt]);
                }
            }
        }
        // write Y (overwrites sc region too — sc consumed above)
        #pragma unroll
        for (int mt = 0; mt < 2; ++mt)
            #pragma unroll
            for (int r = 0; r < 4; ++r) {
                int row = rh32 + mt * 16 + quad * 4 + r;
                #pragma unroll
                for (int nt = 0; nt < 2; ++nt)
                    y_s[row * Y_W + wc * 32 + nt * 16 + nl] =
                        f2bf(tanh_fast(acc1[mt][nt][r]));
            }
        // ---- U ring prologue (long lead: rides through G2)
        ISSUE_U(0); ISSUE_U(1); ISSUE_U(2); ISSUE_U(3); ISSUE_U(4);
        LBAR();                              // C: Y published

        // ---- Gv = sum_e g[row][e]
        float Gv[2][4];
        #pragma unroll
        for (int mt = 0; mt < 2; ++mt)
            #pragma unroll
            for (int r = 0; r < 4; ++r) {
                int row = rh32 + mt * 16 + quad * 4 + r;
                f32x4 g4 = *reinterpret_cast<const f32x4*>(&g_s[row * ENUM]);
                Gv[mt][r] = g4[0] + g4[1] + g4[2] + g4[3];
            }

        // ---- GEMM2: z = g ⊙ tanh(Y_e @ C_e^T), C from registers
        f32x4 acc2[2][2];
        acc2[0][0] = (f32x4)0.f; acc2[0][1] = (f32x4)0.f;
        acc2[1][0] = (f32x4)0.f; acc2[1][1] = (f32x4)0.f;
        #pragma unroll
        for (int ks = 0; ks < 2; ++ks) {
            bf16x8 a0 = *reinterpret_cast<const bf16x8*>(
                &y_s[(rh32 + nl) * Y_W + e * 64 + ks * 32 + quad * 8]);
            bf16x8 a1 = *reinterpret_cast<const bf16x8*>(
                &y_s[(rh32 + 16 + nl) * Y_W + e * 64 + ks * 32 + quad * 8]);
            #pragma unroll
            for (int nt = 0; nt < 2; ++nt) {
                acc2[0][nt] = MFMA(a0, creg[ks][nt], acc2[0][nt]);
                acc2[1][nt] = MFMA(a1, creg[ks][nt], acc2[1][nt]);
            }
        }
        LBAR();                              // D: all Y reads done
        #pragma unroll
        for (int mt = 0; mt < 2; ++mt)
            #pragma unroll
            for (int r = 0; r < 4; ++r) {
                int row = rh32 + mt * 16 + quad * 4 + r;
                float gv = g_s[row * ENUM + e];
                #pragma unroll
                for (int nt = 0; nt < 2; ++nt)
                    y_s[row * Y_W + e * 64 + h * 32 + nt * 16 + nl] =
                        f2bf(tanh_fast(acc2[mt][nt][r]) * gv);
            }
        // (z published by GEMM3 slice-0's barrier)

        // ---- GEMM3: core = z @ U'^T; 32 quarter-ks slices
        f32x4 acc3[2][4];
        #pragma unroll
        for (int mt = 0; mt < 2; ++mt)
            #pragma unroll
            for (int nt = 0; nt < 4; ++nt) acc3[mt][nt] = (f32x4)0.f;
        #pragma unroll
        for (int s = 0; s < 32; ++s) {
            wait_left(31 - s);
            LBAR();                          // slice s ready; slot free
            if (s + 5 < 32) { ISSUE_U(s + 5); }
            if ((s & 3) == myq3) {
                const int ks = s >> 2;
                bf16x8 za0 = *reinterpret_cast<const bf16x8*>(
                    &y_s[(rh32 + nl) * Y_W + ks * 32 + quad * 8]);
                bf16x8 za1 = *reinterpret_cast<const bf16x8*>(
                    &y_s[(rh32 + 16 + nl) * Y_W + ks * 32 + quad * 8]);
                const us* sl = stg_s + (s % 6) * 4096;
                #pragma unroll
                for (int nt = 0; nt < 4; ++nt) {
                    bf16x8 b = *reinterpret_cast<const bf16x8*>(
                        &sl[(jb3 + nt) * 512 + lane * 8]);
                    acc3[0][nt] = MFMA(za0, b, acc3[0][nt]);
                    acc3[1][nt] = MFMA(za1, b, acc3[1][nt]);
                }
            }
        }

        // ---- bias (loaded post-drain: outside the pipeline's vmcnt window)
        float bias_r[4];
        #pragma unroll
        for (int nt = 0; nt < 4; ++nt)
            bias_r[nt] = bl[wc * 64 + nt * 16 + nl];

        // ---- epilogue: xl = xl + x0 * (core + bias*G)
        #pragma unroll
        for (int nt = 0; nt < 4; ++nt) {
            int col = wc * 64 + nt * 16 + nl;
            #pragma unroll
            for (int mt = 0; mt < 2; ++mt)
                #pragma unroll
                for (int r = 0; r < 4; ++r) {
                    int row = rh32 + mt * 16 + quad * 4 + r;
                    float x0v = bf2f(
                        (us)(x0p[mt][nt][r >> 1] >> ((r & 1) * 16)));
                    float xlo = bf2f(xl_s[row * XL_W + col]);
                    float res = xlo
                              + x0v * (acc3[mt][nt][r] + bias_r[nt] * Gv[mt][r]);
                    if (layer == CROSS - 1)
                        out[(size_t)(row0 + row) * DIM + col] = res;
                    else
                        xl_s[row * XL_W + col] = f2bf(res);
                }
        }
        // next layer's barrier A publishes xl_s
    }
#undef ISSUE_V
#undef ISSUE_U
}

// ---------------------------------------------------------------------------
extern "C" void kernel_launch(void* const* d_in, const int* in_sizes, int n_in,
                              void* d_out, int out_size, void* d_ws,
                              size_t ws_size, hipStream_t stream) {
    const float* x      = (const float*)d_in[0];
    const float* Vs     = (const float*)d_in[1];
    const float* Cs     = (const float*)d_in[2];
    const float* Us     = (const float*)d_in[3];
    const float* bias   = (const float*)d_in[4];
    const float* gate_w = (const float*)d_in[5];
    float* out = (float*)d_out;

    us* Vf = (us*)d_ws;                                   // 393216 bf16
    us* Uf = Vf + (size_t)CROSS * ELD * DIM;              // 393216
    us* Cf = Uf + (size_t)CROSS * DIM * ELD;              // 49152

    swz_all<<<1632, 64, 0, stream>>>(Vs, Cs, Us, Vf, Cf, Uf);
    dcn_fused<<<BATCH / BT, NTHR, 0, stream>>>(x, out, Vf, Cf, Uf,
                                               gate_w, bias);
}

// Round 10
// 390.444 us; speedup vs baseline: 1.0276x; 1.0276x over previous
//
#include <hip/hip_runtime.h>
#include <hip/hip_bf16.h>

// DCNv2 CrossNet on MI355X — fused 3-layer kernel, v13.
// Thesis (from 9 rounds of counters): the wall is the shared per-CU LDS
// pipe (~3.7k ds-instrs/CU/layer at ~10-12 cyc each ~= 50% of runtime)
// plus unhidden phase-boundary stalls with ONE resident block. Fix: TWO
// independent blocks/CU so one block's compute covers the other's stalls.
// BT=32 / 8 waves / 2 blocks/CU / grid 1024 = 2 clean rounds.
// At this geometry every V/U fragment is consumed by exactly ONE wave ->
// wave-private rings are LOAD-ONCE (no v10-style duplication).
// Sync: v11's proven discipline — lgkm-only barriers (LBAR, no vmcnt
// drain), counted vmcnt on 3-slot/1KB wave-private rings, creg issued
// BEFORE the ring prologue so in-order retirement keeps constants exact,
// bias loaded after the G3 drain. Epilogue keeps the xl residual in
// REGISTERS (xlr) — kills 32 scalar LDS reads/thread/layer. Plain x loads
// (nontemporal regressed traffic on both counters). Gate = uniform VALU
// dot; sc partials alias y_s. LDS 79360 B -> 2 blocks/CU.
//
// Shapes: x[32768,512]; Vs[3,4,64,512]; Cs[3,4,64,64]; Us[3,4,512,64];
//         bias[3,512]; gate_w[512,4].

#define CROSS   3
#define ENUM    4
#define LR      64
#define ELD     256     // ENUM*LR
#define DIM     512
#define BATCH   32768
#define BT      32      // batch rows per block
#define NTHR    512     // 8 waves

#define XL_W    520     // 512 + 8 pad (shorts)
#define Y_W     264     // 256 + 8 pad (shorts)

typedef __bf16 bf16x8 __attribute__((ext_vector_type(8)));
typedef float  f32x4  __attribute__((ext_vector_type(4)));
typedef unsigned short us;
typedef unsigned short us4 __attribute__((ext_vector_type(4)));

__device__ __forceinline__ us f2bf(float f) {
    return __builtin_bit_cast(us, (__bf16)f);
}
__device__ __forceinline__ float bf2f(us b) {
    unsigned int u = ((unsigned int)b) << 16;
    return __builtin_bit_cast(float, u);
}
__device__ __forceinline__ unsigned int pack2(float lo, float hi) {
    return (unsigned int)f2bf(lo) | ((unsigned int)f2bf(hi) << 16);
}
// fast tanh: (e^2x - 1) / (e^2x + 1); inputs bounded by 0.05-scaled weights.
__device__ __forceinline__ float tanh_fast(float x) {
    float t = __expf(2.f * x);
    return (t - 1.f) * __builtin_amdgcn_rcpf(t + 1.f);
}

#define MFMA(a, b, c) __builtin_amdgcn_mfma_f32_16x16x32_bf16(a, b, c, 0, 0, 0)

// async global->LDS copy, 16 B per lane. LDS dest wave-uniform; HW writes
// lane l at dst + l*16. Global src is per-lane.
__device__ __forceinline__ void gload_lds16(const us* g, us* l) {
    __builtin_amdgcn_global_load_lds(
        (const __attribute__((address_space(1))) unsigned int*)g,
        (__attribute__((address_space(3))) unsigned int*)l, 16, 0, 0);
}

#define WAITN(n)  asm volatile("s_waitcnt vmcnt(" #n ")" ::: "memory")
#define SBAR0()   __builtin_amdgcn_sched_barrier(0)
// Barrier that does NOT drain vmcnt: ds-visibility (lgkmcnt) + s_barrier.
#define LBAR() do { SBAR0(); \
    asm volatile("s_waitcnt lgkmcnt(0)" ::: "memory"); \
    __builtin_amdgcn_s_barrier(); SBAR0(); } while (0)

// counted ring wait: `left` = min(2, frags not yet required). Constant-folds.
__device__ __forceinline__ void wait_slot(int left) {
    if (left >= 2)      WAITN(2);
    else if (left == 1) WAITN(1);
    else                WAITN(0);
}

// ---------------------------------------------------------------------------
// Swizzle prepass: fp32 weights -> bf16 MFMA-B fragment order, vectorized.
// frag[nt][ks][lane][8]: n = nt*16 + (lane&15), k = ks*32 + (lane>>4)*8 + j.
// ---------------------------------------------------------------------------
__global__ __launch_bounds__(64) void swz_all(
    const float* __restrict__ Vs, const float* __restrict__ Cs,
    const float* __restrict__ Us,
    us* __restrict__ Vf, us* __restrict__ Cf, us* __restrict__ Uf)
{
    int b = blockIdx.x;
    int lane = threadIdx.x;
    const float* src;
    us* dst;
    if (b < 768) {                       // V: [3][16 nt][16 ks]
        int i = b >> 8, t = b & 255;
        int nt = t >> 4, ks = t & 15;
        int n  = nt * 16 + (lane & 15);
        int k0 = ks * 32 + (lane >> 4) * 8;
        src = Vs + (size_t)i * ELD * DIM + (size_t)n * DIM + k0;
        dst = Vf + (size_t)i * ELD * DIM
            + ((size_t)(nt * 16 + ks) * 64 + lane) * 8;
    } else if (b < 1536) {               // U': [3][32 nt][8 ks], k = e*64+l
        int bb = b - 768;
        int i = bb >> 8, t = bb & 255;
        int nt = t >> 3, ks = t & 7;
        int n  = nt * 16 + (lane & 15);            // d
        int k0 = ks * 32 + (lane >> 4) * 8;        // e*64 + l
        int e = k0 >> 6, l0 = k0 & 63;
        src = Us + (size_t)i * ENUM * DIM * LR
            + (size_t)e * DIM * LR + (size_t)n * LR + l0;
        dst = Uf + (size_t)i * DIM * ELD
            + ((size_t)(nt * 8 + ks) * 64 + lane) * 8;
    } else {                             // C: [3][4 e][4 nt][2 ks]
        int bb = b - 1536;
        int i = bb >> 5, rest = bb & 31;
        int e = rest >> 3, t = rest & 7;
        int nt = t >> 1, ks = t & 1;
        int n  = nt * 16 + (lane & 15);
        int k0 = ks * 32 + (lane >> 4) * 8;
        src = Cs + (((size_t)(i * ENUM + e) * LR + n) * LR) + k0;
        dst = Cf + (size_t)i * ENUM * LR * LR
            + ((size_t)((e * 4 + nt) * 2 + ks) * 64 + lane) * 8;
    }
    f32x4 s0 = *reinterpret_cast<const f32x4*>(src);
    f32x4 s1 = *reinterpret_cast<const f32x4*>(src + 4);
    us4 p0, p1;
    p0[0] = f2bf(s0[0]); p0[1] = f2bf(s0[1]); p0[2] = f2bf(s0[2]); p0[3] = f2bf(s0[3]);
    p1[0] = f2bf(s1[0]); p1[1] = f2bf(s1[1]); p1[2] = f2bf(s1[2]); p1[3] = f2bf(s1[3]);
    *reinterpret_cast<us4*>(dst)     = p0;
    *reinterpret_cast<us4*>(dst + 4) = p1;
}

// ---------------------------------------------------------------------------
// Fused 3-layer kernel. Block: 32 rows, 512 threads (8 waves), 2 blocks/CU.
// Thread ownership (16x16x32 D-layout, mt in 0..1):
//   row = mt*16 + quad*4 + r,  col(G3) = wc*64 + nt*16 + nl.
// G1: wave wc owns Y cols [wc*32,+32); V frags wc*2+nt are PRIVATE to this
//   wave (load-once). G2: e = wc>>1, h = wc&1; C from registers.
// G3: wave owns cols [wc*64,+64); U frags wc*4+nt private.
// Ring: 3 x 1KB slots/wave; issue frag f+3 into slot (f+3)%3 (== f%3, safe:
//   the slot's ds_read retired before the MFMA that precedes the issue);
//   steady wait vmcnt(2) (creg retire first, in-order). Barriers: 5/layer,
//   all lgkm-only — ring loads fly across them.
// ---------------------------------------------------------------------------
__global__ __launch_bounds__(NTHR, 4) void dcn_fused(
    const float* __restrict__ x,
    float* __restrict__ out,
    const us* __restrict__ Vf,
    const us* __restrict__ Cf,
    const us* __restrict__ Uf,
    const float* __restrict__ gw,
    const float* __restrict__ bias)
{
    __shared__ us xl_s[BT * XL_W];                   // 33280 B
    __shared__ __align__(16) us y_s[BT * Y_W];       // 16896 B (sc | Y | z)
    __shared__ us ring_s[8 * 1536];                  // 24576 B, 3KB/wave
    __shared__ us gw_s[4 * 512];                     // 4096 B, gate_w [e][d]
    __shared__ __align__(16) float g_s[BT * ENUM];   // 512 B
    // total 79360 B -> 2 blocks/CU, 16 waves/CU (4/SIMD)
    float* sc = reinterpret_cast<float*>(y_s);       // gate partials alias

    const int tid  = threadIdx.x;
    const int wave = tid >> 6, lane = tid & 63;
    const int quad = lane >> 4, nl = lane & 15;
    const int wc   = wave;
    const int row0 = blockIdx.x * BT;
    us* wring = &ring_s[wave * 1536];

#define ISSUE_V(f) gload_lds16( \
    Vl + ((size_t)((wc * 2 + ((f) & 1)) * 16 + ((f) >> 1)) * 64 + lane) * 8, \
    wring + ((f) % 3) * 512)
#define ISSUE_U(f) gload_lds16( \
    Ul + ((size_t)((wc * 4 + ((f) & 3)) * 8 + ((f) >> 2)) * 64 + lane) * 8, \
    wring + ((f) % 3) * 512)

    // ---- stage x -> xl_s (bf16): 32*128 = 4096 float4s, 8 per thread
    #pragma unroll
    for (int it = 0; it < 8; ++it) {
        int f4 = tid + it * NTHR;            // 0..4095
        int r = f4 >> 7, c4 = f4 & 127;
        f32x4 v = *reinterpret_cast<const f32x4*>(
            x + (size_t)(row0 + r) * DIM + c4 * 4);
        us4 p;
        p[0] = f2bf(v[0]); p[1] = f2bf(v[1]); p[2] = f2bf(v[2]); p[3] = f2bf(v[3]);
        *reinterpret_cast<us4*>(&xl_s[r * XL_W + c4 * 4]) = p;
    }
    // ---- stage gate_w -> gw_s[e][d] (bf16), 4 elems/thread
    #pragma unroll
    for (int j = 0; j < 4; ++j) {
        int idx = tid * 4 + j;               // 0..2047
        int e = idx >> 9, d = idx & 511;
        gw_s[idx] = f2bf(gw[(size_t)d * ENUM + e]);
    }
    LBAR();                                  // entry: xl_s + gw_s published

    // ---- x0 + xl residual, packed bf16 in regs (ownership elements)
    unsigned int x0p[2][4][2];
    unsigned int xlr[2][4][2];
    #pragma unroll
    for (int mt = 0; mt < 2; ++mt)
        #pragma unroll
        for (int nt = 0; nt < 4; ++nt) {
            int rb = mt * 16 + quad * 4;
            int col = wc * 64 + nt * 16 + nl;
            unsigned int b0 = xl_s[(rb + 0) * XL_W + col];
            unsigned int b1 = xl_s[(rb + 1) * XL_W + col];
            unsigned int b2 = xl_s[(rb + 2) * XL_W + col];
            unsigned int b3 = xl_s[(rb + 3) * XL_W + col];
            x0p[mt][nt][0] = b0 | (b1 << 16);
            x0p[mt][nt][1] = b2 | (b3 << 16);
            xlr[mt][nt][0] = x0p[mt][nt][0];
            xlr[mt][nt][1] = x0p[mt][nt][1];
        }

    const int e = wc >> 1, h = wc & 1;       // GEMM2 roles

    #pragma unroll 1
    for (int layer = 0; layer < CROSS; ++layer) {
        const us* Vl = Vf + (size_t)layer * ELD * DIM;
        const us* Cl = Cf + (size_t)layer * ENUM * LR * LR;
        const us* Ul = Uf + (size_t)layer * DIM * ELD;
        const float* bl = bias + layer * DIM;

        // ---- C fragments FIRST (retire before V0; keeps ring counts exact)
        bf16x8 creg[2][2];
        #pragma unroll
        for (int ks = 0; ks < 2; ++ks)
            #pragma unroll
            for (int nt = 0; nt < 2; ++nt)
                creg[ks][nt] = *reinterpret_cast<const bf16x8*>(
                    &Cl[((size_t)((e * 4 + h * 2 + nt) * 2 + ks) * 64 + lane) * 8]);
        // ---- V ring prologue
        ISSUE_V(0); ISSUE_V(1); ISSUE_V(2);
        LBAR();                              // A: xl_s published (no vm drain)

        // ---- gate partials: thread (row, e, quarter) does 128 MACs
        {
            int grow = tid >> 4, ge = (tid >> 2) & 3, gq = tid & 3;
            float gp = 0.f;
            #pragma unroll
            for (int dd = 0; dd < 16; ++dd) {
                int d0 = gq * 128 + ((dd + gq * 4) & 15) * 8;
                bf16x8 xa = *reinterpret_cast<const bf16x8*>(
                    &xl_s[grow * XL_W + d0]);
                bf16x8 wa = *reinterpret_cast<const bf16x8*>(
                    &gw_s[ge * 512 + d0]);
                #pragma unroll
                for (int j = 0; j < 8; ++j)
                    gp += (float)xa[j] * (float)wa[j];
            }
            sc[tid] = gp;
        }
        LBAR();                              // B: partials published
        if (tid < 128)
            g_s[tid] = sc[tid * 4] + sc[tid * 4 + 1]
                     + sc[tid * 4 + 2] + sc[tid * 4 + 3];

        // ---- GEMM1: Y = tanh(xl @ V^T); wave-private ring, no barriers
        f32x4 acc1[2][2];
        acc1[0][0] = (f32x4)0.f; acc1[0][1] = (f32x4)0.f;
        acc1[1][0] = (f32x4)0.f; acc1[1][1] = (f32x4)0.f;
        #pragma unroll
        for (int ks = 0; ks < 16; ++ks) {
            bf16x8 a0 = *reinterpret_cast<const bf16x8*>(
                &xl_s[(nl) * XL_W + ks * 32 + quad * 8]);
            bf16x8 a1 = *reinterpret_cast<const bf16x8*>(
                &xl_s[(16 + nl) * XL_W + ks * 32 + quad * 8]);
            #pragma unroll
            for (int nt = 0; nt < 2; ++nt) {
                const int f = ks * 2 + nt;
                wait_slot(31 - f);
                SBAR0();
                bf16x8 b = *reinterpret_cast<const bf16x8*>(
                    &wring[(f % 3) * 512 + lane * 8]);
                acc1[0][nt] = MFMA(a0, b, acc1[0][nt]);
                acc1[1][nt] = MFMA(a1, b, acc1[1][nt]);
                SBAR0();
                if (f + 3 < 32) { ISSUE_V(f + 3); }
            }
        }
        // write Y (sc region consumed above)
        #pragma unroll
        for (int mt = 0; mt < 2; ++mt)
            #pragma unroll
            for (int r = 0; r < 4; ++r) {
                int row = mt * 16 + quad * 4 + r;
                #pragma unroll
                for (int nt = 0; nt < 2; ++nt)
                    y_s[row * Y_W + wc * 32 + nt * 16 + nl] =
                        f2bf(tanh_fast(acc1[mt][nt][r]));
            }
        // ---- U ring prologue (rides through C barrier + G2)
        ISSUE_U(0); ISSUE_U(1); ISSUE_U(2);
        LBAR();                              // C: Y + g ready (no vm drain)

        // ---- Gv = sum_e g[row][e]
        float Gv[2][4];
        #pragma unroll
        for (int mt = 0; mt < 2; ++mt)
            #pragma unroll
            for (int r = 0; r < 4; ++r) {
                int row = mt * 16 + quad * 4 + r;
                f32x4 g4 = *reinterpret_cast<const f32x4*>(&g_s[row * ENUM]);
                Gv[mt][r] = g4[0] + g4[1] + g4[2] + g4[3];
            }

        // ---- GEMM2: z = g ⊙ tanh(Y_e @ C_e^T), C from registers
        f32x4 acc2[2][2];
        acc2[0][0] = (f32x4)0.f; acc2[0][1] = (f32x4)0.f;
        acc2[1][0] = (f32x4)0.f; acc2[1][1] = (f32x4)0.f;
        #pragma unroll
        for (int ks = 0; ks < 2; ++ks) {
            bf16x8 a0 = *reinterpret_cast<const bf16x8*>(
                &y_s[(nl) * Y_W + e * 64 + ks * 32 + quad * 8]);
            bf16x8 a1 = *reinterpret_cast<const bf16x8*>(
                &y_s[(16 + nl) * Y_W + e * 64 + ks * 32 + quad * 8]);
            #pragma unroll
            for (int nt = 0; nt < 2; ++nt) {
                acc2[0][nt] = MFMA(a0, creg[ks][nt], acc2[0][nt]);
                acc2[1][nt] = MFMA(a1, creg[ks][nt], acc2[1][nt]);
            }
        }
        LBAR();                              // D: all Y reads done
        #pragma unroll
        for (int mt = 0; mt < 2; ++mt)
            #pragma unroll
            for (int r = 0; r < 4; ++r) {
                int row = mt * 16 + quad * 4 + r;
                float gv = g_s[row * ENUM + e];
                #pragma unroll
                for (int nt = 0; nt < 2; ++nt)
                    y_s[row * Y_W + e * 64 + h * 32 + nt * 16 + nl] =
                        f2bf(tanh_fast(acc2[mt][nt][r]) * gv);
            }
        LBAR();                              // E: z ready

        // ---- GEMM3: core = z @ U'^T, K=256; wave-private ring
        f32x4 acc3[2][4];
        #pragma unroll
        for (int mt = 0; mt < 2; ++mt)
            #pragma unroll
            for (int nt = 0; nt < 4; ++nt) acc3[mt][nt] = (f32x4)0.f;
        #pragma unroll
        for (int ks = 0; ks < 8; ++ks) {
            bf16x8 a0 = *reinterpret_cast<const bf16x8*>(
                &y_s[(nl) * Y_W + ks * 32 + quad * 8]);
            bf16x8 a1 = *reinterpret_cast<const bf16x8*>(
                &y_s[(16 + nl) * Y_W + ks * 32 + quad * 8]);
            #pragma unroll
            for (int nt = 0; nt < 4; ++nt) {
                const int f = ks * 4 + nt;
                wait_slot(31 - f);
                SBAR0();
                bf16x8 b = *reinterpret_cast<const bf16x8*>(
                    &wring[(f % 3) * 512 + lane * 8]);
                acc3[0][nt] = MFMA(a0, b, acc3[0][nt]);
                acc3[1][nt] = MFMA(a1, b, acc3[1][nt]);
                SBAR0();
                if (f + 3 < 32) { ISSUE_U(f + 3); }
            }
        }

        // ---- bias (outside the ring's vmcnt window: ring drained at tail)
        float bias_r[4];
        #pragma unroll
        for (int nt = 0; nt < 4; ++nt)
            bias_r[nt] = bl[wc * 64 + nt * 16 + nl];

        // ---- epilogue: xl = xl + x0 * (core + bias*G); xl from REGISTERS
        #pragma unroll
        for (int nt = 0; nt < 4; ++nt) {
            int col = wc * 64 + nt * 16 + nl;
            #pragma unroll
            for (int mt = 0; mt < 2; ++mt) {
                float res[4];
                #pragma unroll
                for (int r = 0; r < 4; ++r) {
                    int row = mt * 16 + quad * 4 + r;
                    float x0v = bf2f(
                        (us)(x0p[mt][nt][r >> 1] >> ((r & 1) * 16)));
                    float xlo = bf2f(
                        (us)(xlr[mt][nt][r >> 1] >> ((r & 1) * 16)));
                    res[r] = xlo
                           + x0v * (acc3[mt][nt][r] + bias_r[nt] * Gv[mt][r]);
                    if (layer == CROSS - 1)
                        out[(size_t)(row0 + row) * DIM + col] = res[r];
                    else
                        xl_s[row * XL_W + col] = f2bf(res[r]);
                }
                if (layer < CROSS - 1) {
                    xlr[mt][nt][0] = pack2(res[0], res[1]);
                    xlr[mt][nt][1] = pack2(res[2], res[3]);
                }
            }
        }
        // next layer's barrier A publishes xl_s
    }
#undef ISSUE_V
#undef ISSUE_U
}

// ---------------------------------------------------------------------------
extern "C" void kernel_launch(void* const* d_in, const int* in_sizes, int n_in,
                              void* d_out, int out_size, void* d_ws,
                              size_t ws_size, hipStream_t stream) {
    const float* x      = (const float*)d_in[0];
    const float* Vs     = (const float*)d_in[1];
    const float* Cs     = (const float*)d_in[2];
    const float* Us     = (const float*)d_in[3];
    const float* bias   = (const float*)d_in[4];
    const float* gate_w = (const float*)d_in[5];
    float* out = (float*)d_out;

    us* Vf = (us*)d_ws;                                   // 393216 bf16
    us* Uf = Vf + (size_t)CROSS * ELD * DIM;              // 393216
    us* Cf = Uf + (size_t)CROSS * DIM * ELD;              // 49152

    swz_all<<<1632, 64, 0, stream>>>(Vs, Cs, Us, Vf, Cf, Uf);
    dcn_fused<<<BATCH / BT, NTHR, 0, stream>>>(x, out, Vf, Cf, Uf,
                                               gate_w, bias);
}